// Round 6
// baseline (108.623 us; speedup 1.0000x reference)
//
#include <hip/hip_runtime.h>
#include <hip/hip_bf16.h>

typedef __attribute__((ext_vector_type(4))) float f32x4;
typedef __attribute__((ext_vector_type(8))) short bf16x8;

static __device__ __forceinline__ unsigned short f2bf(float f) {
  union { float f; unsigned u; } v;
  v.f = f;
  unsigned r = v.u + 0x7FFFu + ((v.u >> 16) & 1u);
  return (unsigned short)(r >> 16);
}

static __device__ __forceinline__ unsigned cvt_pk_bf16(float lo, float hi) {
  unsigned r;
  asm("v_cvt_pk_bf16_f32 %0, %1, %2" : "=v"(r) : "v"(lo), "v"(hi));
  return r;
}

static __device__ __forceinline__ void gload16(const void* g, void* lds) {
  __builtin_amdgcn_global_load_lds(
      (const __attribute__((address_space(1))) unsigned int*)g,
      (__attribute__((address_space(3))) unsigned int*)lds, 16, 0, 0);
}

// ---------------- fused prep: cast x, transpose+cast w_qkv / w_out ----------------
__global__ __launch_bounds__(256) void prep_kernel(
    const float* __restrict__ x, const float* __restrict__ w_qkv,
    const float* __restrict__ w_out, unsigned short* __restrict__ xb,
    unsigned short* __restrict__ wqkvT, unsigned short* __restrict__ woT) {
  __shared__ float tile[32][33];
  const int bid = blockIdx.x, tid = threadIdx.x;
  if (bid < 4096) {  // cast x -> bf16
    int i = bid * 256 + tid;
    float4 v = reinterpret_cast<const float4*>(x)[i];
    ushort4 o;
    o.x = f2bf(v.x); o.y = f2bf(v.y); o.z = f2bf(v.z); o.w = f2bf(v.w);
    reinterpret_cast<ushort4*>(xb)[i] = o;
    return;
  }
  const float* src; unsigned short* dst; int c0, r0, C;
  if (bid < 7168) {
    int t = bid - 4096;
    src = w_qkv; dst = wqkvT; C = 3072;
    c0 = (t % 96) * 32; r0 = (t / 96) * 32;
  } else {
    int t = bid - 7168;
    src = w_out; dst = woT; C = 1024;
    c0 = (t & 31) * 32; r0 = (t >> 5) * 32;
  }
  int tx = tid & 31, ty = tid >> 5;
#pragma unroll
  for (int i = 0; i < 32; i += 8)
    tile[ty + i][tx] = src[(size_t)(r0 + ty + i) * C + c0 + tx];
  __syncthreads();
#pragma unroll
  for (int i = 0; i < 32; i += 8)
    dst[(size_t)(c0 + ty + i) * 1024 + r0 + tx] = f2bf(tile[tx][ty + i]);
}

// ---------------- bf16 GEMM, 128xBN tile, BK=32, 2-phase prefetch ----------------
template <int MODE, int BN>
__global__ __launch_bounds__(256, MODE == 0 ? 3 : 2) void gemm_bf16(
    const unsigned short* __restrict__ A,
    const unsigned short* __restrict__ Bt,
    const float* __restrict__ bias,
    unsigned short* __restrict__ q_out,
    unsigned short* __restrict__ k_out,
    unsigned short* __restrict__ v_out,
    float* __restrict__ f_out) {
  constexpr int NB2 = BN / 32;
  constexpr int NBL = BN / 64;
  __shared__ __align__(16) unsigned short As[2][128 * 32];
  __shared__ __align__(16) unsigned short Bs[2][BN * 32];

  const int tid = threadIdx.x;
  const int wid = tid >> 6, lane = tid & 63;
  const int l15 = lane & 15, g = lane >> 4;
  const int wm = wid >> 1, wn = wid & 1;
  const int n0 = blockIdx.x * BN, m0 = blockIdx.y * 128;

  f32x4 acc[4][NB2] = {};

  auto stage = [&](int k0, int bsel) {
#pragma unroll
    for (int i = 0; i < 2; ++i) {
      int t = tid + i * 256;
      int row = t >> 2, c8 = (t & 3) << 3;
      gload16(A + (size_t)(m0 + row) * 1024 + k0 + c8, &As[bsel][(i * 256 + wid * 64) * 8]);
    }
#pragma unroll
    for (int i = 0; i < NBL; ++i) {
      int t = tid + i * 256;
      int row = t >> 2, c8 = (t & 3) << 3;
      gload16(Bt + (size_t)(n0 + row) * 1024 + k0 + c8, &Bs[bsel][(i * 256 + wid * 64) * 8]);
    }
  };

  stage(0, 0);
  __syncthreads();
  for (int ks = 0; ks < 32; ++ks) {
    const int cur = ks & 1;
    if (ks + 1 < 32) stage((ks + 1) * 32, cur ^ 1);
    bf16x8 a[4], b[NB2];
#pragma unroll
    for (int mi = 0; mi < 4; ++mi)
      a[mi] = *reinterpret_cast<const bf16x8*>(&As[cur][(wm * 64 + mi * 16 + l15) * 32 + g * 8]);
#pragma unroll
    for (int ni = 0; ni < NB2; ++ni)
      b[ni] = *reinterpret_cast<const bf16x8*>(&Bs[cur][(wn * (BN / 2) + ni * 16 + l15) * 32 + g * 8]);
    __builtin_amdgcn_s_setprio(1);
#pragma unroll
    for (int mi = 0; mi < 4; ++mi)
#pragma unroll
      for (int ni = 0; ni < NB2; ++ni)
        acc[mi][ni] = __builtin_amdgcn_mfma_f32_16x16x32_bf16(a[mi], b[ni], acc[mi][ni], 0, 0, 0);
    __builtin_amdgcn_s_setprio(0);
    __syncthreads();
  }

  if (MODE == 0) {
    const int which = n0 >> 10;
    unsigned short* dst = (which == 0) ? q_out : (which == 1) ? k_out : v_out;
    const float oscale = (which == 0) ? 0.125f * 1.44269504f : 1.0f;
#pragma unroll
    for (int ni = 0; ni < NB2; ++ni) {
      int col = n0 + wn * (BN / 2) + ni * 16 + l15;
      int c = col & 1023;
      int h = c >> 6, d = c & 63;
      float bv = bias[col];
#pragma unroll
      for (int mi = 0; mi < 4; ++mi) {
#pragma unroll
        for (int r = 0; r < 4; ++r) {
          int rowg = m0 + wm * 64 + mi * 16 + g * 4 + r;
          int bb = rowg >> 11, tt = rowg & 2047;
          dst[((bb * 16 + h) * 2048 + tt) * 64 + d] = f2bf((acc[mi][ni][r] + bv) * oscale);
        }
      }
    }
  } else {
#pragma unroll
    for (int ni = 0; ni < NB2; ++ni) {
      int col = n0 + wn * (BN / 2) + ni * 16 + l15;
      float bv = bias[col];
#pragma unroll
      for (int mi = 0; mi < 4; ++mi)
#pragma unroll
        for (int r = 0; r < 4; ++r) {
          int rowg = m0 + wm * 64 + mi * 16 + g * 4 + r;
          f_out[(size_t)rowg * 1024 + col] = acc[mi][ni][r] + bv;
        }
    }
  }
}

// ---------------- causal flash attention: concurrent paired q-tiles ----------------
// Q,K,V: [BH=32][T=2048][D=64] bf16 (Q pre-scaled by 0.125*log2e).
// Block lin: pi = lin>>5 (0..15), bh = lin&31. Tiles A=pi, B=31-pi processed
// CONCURRENTLY over shared staged K/V tiles 0..31-pi. kf/vf fragments shared;
// MFMA doubles per LDS read. Dispatch pi-ascending = longest first (backfill).
#define KS_SZ (64 * 64)
#define VT_SZ (64 * 72)

__device__ __forceinline__ void attn_stage_K(const unsigned short* __restrict__ Kb,
                                             int k0, unsigned short* KsBuf,
                                             int tid, int wid) {
#pragma unroll
  for (int i = 0; i < 2; ++i) {
    int t = tid + i * 256;
    int row = t >> 3;
    int cb = (t & 7) << 4;
    int src = cb ^ ((row & 7) << 4);  // pre-swizzled global source (rule 21)
    gload16((const char*)Kb + (size_t)(k0 + row) * 128 + src,
            (char*)KsBuf + (i * 256 + wid * 64) * 16);
  }
}

__device__ __forceinline__ void write_vt(unsigned short* VtBuf, int kvL, int d8,
                                         uint4 v0, uint4 v1) {
  unsigned* base = reinterpret_cast<unsigned*>(&VtBuf[(size_t)d8 * 72 + kvL]);
  unsigned lo, hi;
  lo = __builtin_amdgcn_perm(v1.x, v0.x, 0x05040100u);
  hi = __builtin_amdgcn_perm(v1.x, v0.x, 0x07060302u);
  base[0] = lo;   base[36] = hi;
  lo = __builtin_amdgcn_perm(v1.y, v0.y, 0x05040100u);
  hi = __builtin_amdgcn_perm(v1.y, v0.y, 0x07060302u);
  base[72] = lo;  base[108] = hi;
  lo = __builtin_amdgcn_perm(v1.z, v0.z, 0x05040100u);
  hi = __builtin_amdgcn_perm(v1.z, v0.z, 0x07060302u);
  base[144] = lo; base[180] = hi;
  lo = __builtin_amdgcn_perm(v1.w, v0.w, 0x05040100u);
  hi = __builtin_amdgcn_perm(v1.w, v0.w, 0x07060302u);
  base[216] = lo; base[252] = hi;
}

__global__ __launch_bounds__(256, 2) void attn_fwd(
    const unsigned short* __restrict__ Q,
    const unsigned short* __restrict__ K,
    const unsigned short* __restrict__ V,
    unsigned short* __restrict__ O) {
  __shared__ __align__(16) unsigned short Ks[2 * KS_SZ];   // 16 KB
  __shared__ __align__(16) unsigned short Vt[2 * VT_SZ];   // 18 KB
  __shared__ __align__(16) unsigned short Ps[2 * 64 * 72]; // 18 KB (A | B)

  const int tid = threadIdx.x;
  const int wid = tid >> 6;
  const int l15 = tid & 15;
  const int g = (tid & 63) >> 4;

  const int lin = blockIdx.x;
  const int pi = lin >> 5, bh = lin & 31;  // pi ascending = long blocks first
  const int b = bh >> 4, h = bh & 15;
  const int q0A = pi << 6, q0B = (31 - pi) << 6;
  const int nB = 32 - pi;  // loop count; tile A active while t <= pi

  const unsigned short* Qb = Q + (size_t)bh * 2048 * 64;
  const unsigned short* Kb = K + (size_t)bh * 2048 * 64;
  const unsigned short* Vb = V + (size_t)bh * 2048 * 64;

  bf16x8 qfA[2], qfB[2];
  {
    const unsigned short* qa = Qb + (size_t)(q0A + wid * 16 + l15) * 64;
    qfA[0] = *reinterpret_cast<const bf16x8*>(qa + g * 8);
    qfA[1] = *reinterpret_cast<const bf16x8*>(qa + 32 + g * 8);
    const unsigned short* qb2 = Qb + (size_t)(q0B + wid * 16 + l15) * 64;
    qfB[0] = *reinterpret_cast<const bf16x8*>(qb2 + g * 8);
    qfB[1] = *reinterpret_cast<const bf16x8*>(qb2 + 32 + g * 8);
  }

  float mA = -1e30f, lA = 0.f, mB = -1e30f, lB = 0.f;
  f32x4 otA[4] = {}, otB[4] = {};
  const int qgA = q0A + wid * 16 + l15;
  const int qgB = q0B + wid * 16 + l15;
  const int kvL = (tid & 31) * 2, d8 = (tid >> 5) * 8;
  const int qrow = wid * 16 + l15;
  unsigned short* PsA = Ps;
  unsigned short* PsB = Ps + 64 * 72;

  attn_stage_K(Kb, 0, Ks, tid, wid);
  {
    const uint4* vp = reinterpret_cast<const uint4*>(Vb + (size_t)kvL * 64 + d8);
    write_vt(Vt, kvL, d8, vp[0], vp[8]);
  }
  __syncthreads();

  for (int t = 0; t < nB; ++t) {
    const unsigned short* KsC = Ks + (t & 1) * KS_SZ;
    const unsigned short* VtC = Vt + (t & 1) * VT_SZ;
    uint4 va, vb;
    const bool pf = (t + 1 < nB);
    const bool hasA = (t <= pi);
    if (pf) {
      attn_stage_K(Kb, (t + 1) << 6, Ks + ((t + 1) & 1) * KS_SZ, tid, wid);
      const uint4* vp = reinterpret_cast<const uint4*>(
          Vb + (size_t)(((t + 1) << 6) + kvL) * 64 + d8);
      va = vp[0];
      vb = vp[8];
    }

    // shared K fragments -> registers once, used by both tiles
    bf16x8 kf[2][4];
#pragma unroll
    for (int kk = 0; kk < 2; ++kk)
#pragma unroll
      for (int mi = 0; mi < 4; ++mi) {
        int row = mi * 16 + l15;
        int cb = (kk * 64 + g * 16) ^ ((row & 7) << 4);
        kf[kk][mi] = *reinterpret_cast<const bf16x8*>((const char*)KsC + row * 128 + cb);
      }

    f32x4 sB[4] = {};
    __builtin_amdgcn_s_setprio(1);
#pragma unroll
    for (int kk = 0; kk < 2; ++kk)
#pragma unroll
      for (int mi = 0; mi < 4; ++mi)
        sB[mi] = __builtin_amdgcn_mfma_f32_16x16x32_bf16(kf[kk][mi], qfB[kk], sB[mi], 0, 0, 0);
    __builtin_amdgcn_s_setprio(0);
    f32x4 sA[4] = {};
    if (hasA) {
      __builtin_amdgcn_s_setprio(1);
#pragma unroll
      for (int kk = 0; kk < 2; ++kk)
#pragma unroll
        for (int mi = 0; mi < 4; ++mi)
          sA[mi] = __builtin_amdgcn_mfma_f32_16x16x32_bf16(kf[kk][mi], qfA[kk], sA[mi], 0, 0, 0);
      __builtin_amdgcn_s_setprio(0);
    }

    // ---- softmax B (diag mask at t == nB-1) ----
    if (t == nB - 1) {
      const int k0 = t << 6;
#pragma unroll
      for (int mi = 0; mi < 4; ++mi)
#pragma unroll
        for (int r = 0; r < 4; ++r) {
          int kvg = k0 + mi * 16 + g * 4 + r;
          sB[mi][r] = (kvg <= qgB) ? sB[mi][r] : -1e30f;
        }
    }
    {
      float pmax = -1e30f;
#pragma unroll
      for (int mi = 0; mi < 4; ++mi)
#pragma unroll
        for (int r = 0; r < 4; ++r) pmax = fmaxf(pmax, sB[mi][r]);
      if (!__all(pmax <= mB + 8.0f)) {
        float tmax = fmaxf(pmax, __shfl_xor(pmax, 16));
        tmax = fmaxf(tmax, __shfl_xor(tmax, 32));
        float m_new = fmaxf(mB, tmax);
        float corr = __builtin_amdgcn_exp2f(mB - m_new);
        lB *= corr;
#pragma unroll
        for (int mi = 0; mi < 4; ++mi)
#pragma unroll
          for (int r = 0; r < 4; ++r) otB[mi][r] *= corr;
        mB = m_new;
      }
      float tsum = 0.f;
#pragma unroll
      for (int mi = 0; mi < 4; ++mi) {
        float p0 = __builtin_amdgcn_exp2f(sB[mi][0] - mB);
        float p1 = __builtin_amdgcn_exp2f(sB[mi][1] - mB);
        float p2 = __builtin_amdgcn_exp2f(sB[mi][2] - mB);
        float p3 = __builtin_amdgcn_exp2f(sB[mi][3] - mB);
        tsum += (p0 + p1) + (p2 + p3);
        uint2 pk;
        pk.x = cvt_pk_bf16(p0, p1);
        pk.y = cvt_pk_bf16(p2, p3);
        *reinterpret_cast<uint2*>((char*)PsB + qrow * 144 + mi * 32 + g * 8) = pk;
      }
      lB += tsum;
    }

    // shared V fragments (issued here so lgkm overlaps softmax-A VALU)
    bf16x8 vf[2][4];
#pragma unroll
    for (int kk = 0; kk < 2; ++kk)
#pragma unroll
      for (int mi = 0; mi < 4; ++mi)
        vf[kk][mi] = *reinterpret_cast<const bf16x8*>(VtC + (mi * 16 + l15) * 72 + kk * 32 + g * 8);

    // ---- softmax A (diag mask at t == pi) ----
    if (hasA) {
      if (t == pi) {
        const int k0 = t << 6;
#pragma unroll
        for (int mi = 0; mi < 4; ++mi)
#pragma unroll
          for (int r = 0; r < 4; ++r) {
            int kvg = k0 + mi * 16 + g * 4 + r;
            sA[mi][r] = (kvg <= qgA) ? sA[mi][r] : -1e30f;
          }
      }
      float pmax = -1e30f;
#pragma unroll
      for (int mi = 0; mi < 4; ++mi)
#pragma unroll
        for (int r = 0; r < 4; ++r) pmax = fmaxf(pmax, sA[mi][r]);
      if (!__all(pmax <= mA + 8.0f)) {
        float tmax = fmaxf(pmax, __shfl_xor(pmax, 16));
        tmax = fmaxf(tmax, __shfl_xor(tmax, 32));
        float m_new = fmaxf(mA, tmax);
        float corr = __builtin_amdgcn_exp2f(mA - m_new);
        lA *= corr;
#pragma unroll
        for (int mi = 0; mi < 4; ++mi)
#pragma unroll
          for (int r = 0; r < 4; ++r) otA[mi][r] *= corr;
        mA = m_new;
      }
      float tsum = 0.f;
#pragma unroll
      for (int mi = 0; mi < 4; ++mi) {
        float p0 = __builtin_amdgcn_exp2f(sA[mi][0] - mA);
        float p1 = __builtin_amdgcn_exp2f(sA[mi][1] - mA);
        float p2 = __builtin_amdgcn_exp2f(sA[mi][2] - mA);
        float p3 = __builtin_amdgcn_exp2f(sA[mi][3] - mA);
        tsum += (p0 + p1) + (p2 + p3);
        uint2 pk;
        pk.x = cvt_pk_bf16(p0, p1);
        pk.y = cvt_pk_bf16(p2, p3);
        *reinterpret_cast<uint2*>((char*)PsA + qrow * 144 + mi * 32 + g * 8) = pk;
      }
      lA += tsum;
    }

    // ---- PV: shared vf, per-tile P fragments ----
    {
      bf16x8 pfrB[2];
      pfrB[0] = *reinterpret_cast<const bf16x8*>(PsB + qrow * 72 + g * 8);
      pfrB[1] = *reinterpret_cast<const bf16x8*>(PsB + qrow * 72 + 32 + g * 8);
      __builtin_amdgcn_s_setprio(1);
#pragma unroll
      for (int kk = 0; kk < 2; ++kk)
#pragma unroll
        for (int mi = 0; mi < 4; ++mi)
          otB[mi] = __builtin_amdgcn_mfma_f32_16x16x32_bf16(vf[kk][mi], pfrB[kk], otB[mi], 0, 0, 0);
      __builtin_amdgcn_s_setprio(0);
    }
    if (hasA) {
      bf16x8 pfrA[2];
      pfrA[0] = *reinterpret_cast<const bf16x8*>(PsA + qrow * 72 + g * 8);
      pfrA[1] = *reinterpret_cast<const bf16x8*>(PsA + qrow * 72 + 32 + g * 8);
      __builtin_amdgcn_s_setprio(1);
#pragma unroll
      for (int kk = 0; kk < 2; ++kk)
#pragma unroll
        for (int mi = 0; mi < 4; ++mi)
          otA[mi] = __builtin_amdgcn_mfma_f32_16x16x32_bf16(vf[kk][mi], pfrA[kk], otA[mi], 0, 0, 0);
      __builtin_amdgcn_s_setprio(0);
    }

    if (pf) write_vt(Vt + ((t + 1) & 1) * VT_SZ, kvL, d8, va, vb);
    __syncthreads();
  }

  // ---- epilogues: A via Ks scratch, B via Vt scratch, one barrier ----
  float ltA = lA + __shfl_xor(lA, 16);
  ltA += __shfl_xor(ltA, 32);
  float invA = 1.0f / ltA;
  float ltB = lB + __shfl_xor(lB, 16);
  ltB += __shfl_xor(ltB, 32);
  float invB = 1.0f / ltB;

#pragma unroll
  for (int mi = 0; mi < 4; ++mi) {
    uint2 pkA, pkB;
    pkA.x = cvt_pk_bf16(otA[mi][0] * invA, otA[mi][1] * invA);
    pkA.y = cvt_pk_bf16(otA[mi][2] * invA, otA[mi][3] * invA);
    pkB.x = cvt_pk_bf16(otB[mi][0] * invB, otB[mi][1] * invB);
    pkB.y = cvt_pk_bf16(otB[mi][2] * invB, otB[mi][3] * invB);
    int b0 = (mi * 32 + g * 8) ^ ((qrow & 7) << 4);
    *reinterpret_cast<uint2*>((char*)Ks + qrow * 128 + b0) = pkA;
    *reinterpret_cast<uint2*>((char*)Vt + qrow * 128 + b0) = pkB;
  }
  __syncthreads();
#pragma unroll
  for (int i = 0; i < 2; ++i) {
    int t = tid + i * 256;
    int row = t >> 3;
    int cb = (t & 7) << 4;
    int sw = cb ^ ((row & 7) << 4);
    bf16x8 vA = *reinterpret_cast<const bf16x8*>((const char*)Ks + row * 128 + sw);
    bf16x8 vB = *reinterpret_cast<const bf16x8*>((const char*)Vt + row * 128 + sw);
    *reinterpret_cast<bf16x8*>(O + ((size_t)(b * 2048 + q0A + row)) * 1024 + h * 64 + (cb >> 1)) = vA;
    *reinterpret_cast<bf16x8*>(O + ((size_t)(b * 2048 + q0B + row)) * 1024 + h * 64 + (cb >> 1)) = vB;
  }
}

// ---------------- launch ----------------
extern "C" void kernel_launch(void* const* d_in, const int* in_sizes, int n_in,
                              void* d_out, int out_size, void* d_ws, size_t ws_size,
                              hipStream_t stream) {
  const float* x = (const float*)d_in[0];
  const float* w_qkv = (const float*)d_in[1];
  const float* b_qkv = (const float*)d_in[2];
  const float* w_out = (const float*)d_in[3];
  const float* b_out = (const float*)d_in[4];
  float* out = (float*)d_out;
  char* ws = (char*)d_ws;

  unsigned short* xb    = (unsigned short*)d_out;            // dead before GEMM2 writes
  unsigned short* wqkvT = (unsigned short*)(ws);             //  6 MB
  unsigned short* woT   = (unsigned short*)(ws + 6291456);   //  2 MB
  unsigned short* q_buf = (unsigned short*)(ws + 8388608);   //  8 MB
  unsigned short* k_buf = (unsigned short*)(ws + 16777216);  //  8 MB
  unsigned short* v_buf = (unsigned short*)(ws + 25165824);  //  8 MB
  unsigned short* aout  = (unsigned short*)(ws + 33554432);  //  8 MB -> 40 MB total

  prep_kernel<<<dim3(8192), dim3(256), 0, stream>>>(x, w_qkv, w_out, xb, wqkvT, woT);

  gemm_bf16<0, 128><<<dim3(24, 32), dim3(256), 0, stream>>>(
      xb, wqkvT, b_qkv, q_buf, k_buf, v_buf, nullptr);

  attn_fwd<<<dim3(512), dim3(256), 0, stream>>>(q_buf, k_buf, v_buf, aout);

  gemm_bf16<1, 64><<<dim3(16, 32), dim3(256), 0, stream>>>(
      aout, woT, b_out, nullptr, nullptr, nullptr, out);
}

// Round 7
// 107.179 us; speedup vs baseline: 1.0135x; 1.0135x over previous
//
#include <hip/hip_runtime.h>
#include <hip/hip_bf16.h>

typedef __attribute__((ext_vector_type(4))) float f32x4;
typedef __attribute__((ext_vector_type(8))) short bf16x8;

static __device__ __forceinline__ unsigned short f2bf(float f) {
  union { float f; unsigned u; } v;
  v.f = f;
  unsigned r = v.u + 0x7FFFu + ((v.u >> 16) & 1u);
  return (unsigned short)(r >> 16);
}

static __device__ __forceinline__ unsigned cvt_pk_bf16(float lo, float hi) {
  unsigned r;
  asm("v_cvt_pk_bf16_f32 %0, %1, %2" : "=v"(r) : "v"(lo), "v"(hi));
  return r;
}

static __device__ __forceinline__ void gload16(const void* g, void* lds) {
  __builtin_amdgcn_global_load_lds(
      (const __attribute__((address_space(1))) unsigned int*)g,
      (__attribute__((address_space(3))) unsigned int*)lds, 16, 0, 0);
}

// ---------------- fused prep: cast x, transpose+cast w_qkv / w_out ----------------
__global__ __launch_bounds__(256) void prep_kernel(
    const float* __restrict__ x, const float* __restrict__ w_qkv,
    const float* __restrict__ w_out, unsigned short* __restrict__ xb,
    unsigned short* __restrict__ wqkvT, unsigned short* __restrict__ woT) {
  __shared__ float tile[32][33];
  const int bid = blockIdx.x, tid = threadIdx.x;
  if (bid < 4096) {  // cast x -> bf16
    int i = bid * 256 + tid;
    float4 v = reinterpret_cast<const float4*>(x)[i];
    ushort4 o;
    o.x = f2bf(v.x); o.y = f2bf(v.y); o.z = f2bf(v.z); o.w = f2bf(v.w);
    reinterpret_cast<ushort4*>(xb)[i] = o;
    return;
  }
  const float* src; unsigned short* dst; int c0, r0, C;
  if (bid < 7168) {
    int t = bid - 4096;
    src = w_qkv; dst = wqkvT; C = 3072;
    c0 = (t % 96) * 32; r0 = (t / 96) * 32;
  } else {
    int t = bid - 7168;
    src = w_out; dst = woT; C = 1024;
    c0 = (t & 31) * 32; r0 = (t >> 5) * 32;
  }
  int tx = tid & 31, ty = tid >> 5;
#pragma unroll
  for (int i = 0; i < 32; i += 8)
    tile[ty + i][tx] = src[(size_t)(r0 + ty + i) * C + c0 + tx];
  __syncthreads();
#pragma unroll
  for (int i = 0; i < 32; i += 8)
    dst[(size_t)(c0 + ty + i) * 1024 + r0 + tx] = f2bf(tile[tx][ty + i]);
}

// ---------------- bf16 GEMM, 128xBN tile, BK=32, 2-phase prefetch ----------------
template <int MODE, int BN>
__global__ __launch_bounds__(256, MODE == 0 ? 3 : 2) void gemm_bf16(
    const unsigned short* __restrict__ A,
    const unsigned short* __restrict__ Bt,
    const float* __restrict__ bias,
    unsigned short* __restrict__ q_out,
    unsigned short* __restrict__ k_out,
    unsigned short* __restrict__ v_out,
    float* __restrict__ f_out) {
  constexpr int NB2 = BN / 32;
  constexpr int NBL = BN / 64;
  __shared__ __align__(16) unsigned short As[2][128 * 32];
  __shared__ __align__(16) unsigned short Bs[2][BN * 32];

  const int tid = threadIdx.x;
  const int wid = tid >> 6, lane = tid & 63;
  const int l15 = lane & 15, g = lane >> 4;
  const int wm = wid >> 1, wn = wid & 1;
  const int n0 = blockIdx.x * BN, m0 = blockIdx.y * 128;

  f32x4 acc[4][NB2] = {};

  auto stage = [&](int k0, int bsel) {
#pragma unroll
    for (int i = 0; i < 2; ++i) {
      int t = tid + i * 256;
      int row = t >> 2, c8 = (t & 3) << 3;
      gload16(A + (size_t)(m0 + row) * 1024 + k0 + c8, &As[bsel][(i * 256 + wid * 64) * 8]);
    }
#pragma unroll
    for (int i = 0; i < NBL; ++i) {
      int t = tid + i * 256;
      int row = t >> 2, c8 = (t & 3) << 3;
      gload16(Bt + (size_t)(n0 + row) * 1024 + k0 + c8, &Bs[bsel][(i * 256 + wid * 64) * 8]);
    }
  };

  stage(0, 0);
  __syncthreads();
  for (int ks = 0; ks < 32; ++ks) {
    const int cur = ks & 1;
    if (ks + 1 < 32) stage((ks + 1) * 32, cur ^ 1);
    bf16x8 a[4], b[NB2];
#pragma unroll
    for (int mi = 0; mi < 4; ++mi)
      a[mi] = *reinterpret_cast<const bf16x8*>(&As[cur][(wm * 64 + mi * 16 + l15) * 32 + g * 8]);
#pragma unroll
    for (int ni = 0; ni < NB2; ++ni)
      b[ni] = *reinterpret_cast<const bf16x8*>(&Bs[cur][(wn * (BN / 2) + ni * 16 + l15) * 32 + g * 8]);
    __builtin_amdgcn_s_setprio(1);
#pragma unroll
    for (int mi = 0; mi < 4; ++mi)
#pragma unroll
      for (int ni = 0; ni < NB2; ++ni)
        acc[mi][ni] = __builtin_amdgcn_mfma_f32_16x16x32_bf16(a[mi], b[ni], acc[mi][ni], 0, 0, 0);
    __builtin_amdgcn_s_setprio(0);
    __syncthreads();
  }

  if (MODE == 0) {
    const int which = n0 >> 10;
    unsigned short* dst = (which == 0) ? q_out : (which == 1) ? k_out : v_out;
    const float oscale = (which == 0) ? 0.125f * 1.44269504f : 1.0f;
#pragma unroll
    for (int ni = 0; ni < NB2; ++ni) {
      int col = n0 + wn * (BN / 2) + ni * 16 + l15;
      int c = col & 1023;
      int h = c >> 6, d = c & 63;
      float bv = bias[col];
#pragma unroll
      for (int mi = 0; mi < 4; ++mi) {
#pragma unroll
        for (int r = 0; r < 4; ++r) {
          int rowg = m0 + wm * 64 + mi * 16 + g * 4 + r;
          int bb = rowg >> 11, tt = rowg & 2047;
          dst[((bb * 16 + h) * 2048 + tt) * 64 + d] = f2bf((acc[mi][ni][r] + bv) * oscale);
        }
      }
    }
  } else {
#pragma unroll
    for (int ni = 0; ni < NB2; ++ni) {
      int col = n0 + wn * (BN / 2) + ni * 16 + l15;
      float bv = bias[col];
#pragma unroll
      for (int mi = 0; mi < 4; ++mi)
#pragma unroll
        for (int r = 0; r < 4; ++r) {
          int rowg = m0 + wm * 64 + mi * 16 + g * 4 + r;
          f_out[(size_t)rowg * 1024 + col] = acc[mi][ni][r] + bv;
        }
    }
  }
}

// ---------------- causal flash attention: 4 blocks/CU (40KB LDS) ----------------
// Q,K,V: [BH=32][T=2048][D=64] bf16 (Q pre-scaled by 0.125*log2e).
// O: [B*T=4096][C=1024] bf16. grid 1024: one 64-row q-tile per block.
// qt schedule: quadruples {31-i, 16+i, 15-i, i} sum to 62 iters -> CU-balanced;
// big tiles dispatch first. lin&31 = bh keeps bh%8 -> XCD L2 grouping.
#define KS_SZ (64 * 64)
#define VT_SZ (64 * 64)

__device__ __forceinline__ void attn_stage_K(const unsigned short* __restrict__ Kb,
                                             int k0, unsigned short* KsBuf,
                                             int tid, int wid) {
#pragma unroll
  for (int i = 0; i < 2; ++i) {
    int t = tid + i * 256;
    int row = t >> 3;
    int cb = (t & 7) << 4;
    int src = cb ^ ((row & 7) << 4);  // pre-swizzled global source (rule 21)
    gload16((const char*)Kb + (size_t)(k0 + row) * 128 + src,
            (char*)KsBuf + (i * 256 + wid * 64) * 16);
  }
}

// V [2 rows kvL,kvL+1][8 d] -> Vt[d][kv], stride 64 + XOR swizzle (both sides)
__device__ __forceinline__ void write_vt(unsigned short* VtBuf, int kvL, int d8,
                                         uint4 v0, uint4 v1) {
  char* base = (char*)VtBuf + (size_t)d8 * 128;
  const int c = kvL * 2;
  unsigned lo, hi;
  lo = __builtin_amdgcn_perm(v1.x, v0.x, 0x05040100u);
  hi = __builtin_amdgcn_perm(v1.x, v0.x, 0x07060302u);
  *reinterpret_cast<unsigned*>(base + 0 * 128 + (c ^ (0 << 4))) = lo;
  *reinterpret_cast<unsigned*>(base + 1 * 128 + (c ^ (1 << 4))) = hi;
  lo = __builtin_amdgcn_perm(v1.y, v0.y, 0x05040100u);
  hi = __builtin_amdgcn_perm(v1.y, v0.y, 0x07060302u);
  *reinterpret_cast<unsigned*>(base + 2 * 128 + (c ^ (2 << 4))) = lo;
  *reinterpret_cast<unsigned*>(base + 3 * 128 + (c ^ (3 << 4))) = hi;
  lo = __builtin_amdgcn_perm(v1.z, v0.z, 0x05040100u);
  hi = __builtin_amdgcn_perm(v1.z, v0.z, 0x07060302u);
  *reinterpret_cast<unsigned*>(base + 4 * 128 + (c ^ (4 << 4))) = lo;
  *reinterpret_cast<unsigned*>(base + 5 * 128 + (c ^ (5 << 4))) = hi;
  lo = __builtin_amdgcn_perm(v1.w, v0.w, 0x05040100u);
  hi = __builtin_amdgcn_perm(v1.w, v0.w, 0x07060302u);
  *reinterpret_cast<unsigned*>(base + 6 * 128 + (c ^ (6 << 4))) = lo;
  *reinterpret_cast<unsigned*>(base + 7 * 128 + (c ^ (7 << 4))) = hi;
}

__global__ __launch_bounds__(256, 4) void attn_fwd(
    const unsigned short* __restrict__ Q,
    const unsigned short* __restrict__ K,
    const unsigned short* __restrict__ V,
    unsigned short* __restrict__ O) {
  __shared__ __align__(16) unsigned short Ks[2 * KS_SZ];  // 16 KB (src-swizzled)
  __shared__ __align__(16) unsigned short Vt[2 * VT_SZ];  // 16 KB (XOR-swizzled)
  __shared__ __align__(16) unsigned short Ps[64 * 64];    //  8 KB (XOR-swizzled)
  // total 40960 B -> 4 blocks/CU

  const int tid = threadIdx.x;
  const int wid = tid >> 6;
  const int l15 = tid & 15;
  const int g = (tid & 63) >> 4;

  const int lin = blockIdx.x;
  const int bh = lin & 31;
  const int o = lin >> 5, oq = o & 7, os = o >> 3;
  // balanced quadruples: {31-i, 16+i, 15-i, i}
  const int qt = (os == 0) ? 31 - oq : (os == 1) ? 16 + oq : (os == 2) ? 15 - oq : oq;
  const int b = bh >> 4, h = bh & 15;
  const int q0 = qt << 6, nt = qt + 1;

  const unsigned short* Qb = Q + (size_t)bh * 2048 * 64;
  const unsigned short* Kb = K + (size_t)bh * 2048 * 64;
  const unsigned short* Vb = V + (size_t)bh * 2048 * 64;

  bf16x8 qf[2];
  {
    const unsigned short* qrow_p = Qb + (size_t)(q0 + wid * 16 + l15) * 64;
    qf[0] = *reinterpret_cast<const bf16x8*>(qrow_p + g * 8);
    qf[1] = *reinterpret_cast<const bf16x8*>(qrow_p + 32 + g * 8);
  }

  float m_run = -1e30f;
  float l_run = 0.0f;  // per-lane partial (16 of the row's 64 P values)
  f32x4 ot[4] = {};
  const int qg = q0 + wid * 16 + l15;
  const int kvL = (tid & 31) * 2, d8 = (tid >> 5) * 8;
  const int qrow = wid * 16 + l15;
  const int sP = (qrow & 7) << 4;  // P/O row swizzle constant

  attn_stage_K(Kb, 0, Ks, tid, wid);
  {
    const uint4* vp = reinterpret_cast<const uint4*>(Vb + (size_t)kvL * 64 + d8);
    write_vt(Vt, kvL, d8, vp[0], vp[8]);
  }
  __syncthreads();

  for (int t = 0; t < nt; ++t) {
    const unsigned short* KsC = Ks + (t & 1) * KS_SZ;
    const unsigned short* VtC = Vt + (t & 1) * VT_SZ;
    uint4 va, vb;
    const bool pf = (t + 1 < nt);
    if (pf) {
      attn_stage_K(Kb, (t + 1) << 6, Ks + ((t + 1) & 1) * KS_SZ, tid, wid);
      const uint4* vp = reinterpret_cast<const uint4*>(
          Vb + (size_t)(((t + 1) << 6) + kvL) * 64 + d8);
      va = vp[0];
      vb = vp[8];
    }

    // S^T = K · Q^T (Q pre-scaled, exp2 space)
    f32x4 s[4] = {};
    __builtin_amdgcn_s_setprio(1);
#pragma unroll
    for (int kk = 0; kk < 2; ++kk)
#pragma unroll
      for (int mi = 0; mi < 4; ++mi) {
        int row = mi * 16 + l15;
        int cb = (kk * 64 + g * 16) ^ ((row & 7) << 4);
        bf16x8 kf = *reinterpret_cast<const bf16x8*>((const char*)KsC + row * 128 + cb);
        s[mi] = __builtin_amdgcn_mfma_f32_16x16x32_bf16(kf, qf[kk], s[mi], 0, 0, 0);
      }
    __builtin_amdgcn_s_setprio(0);

    // causal mask on diagonal tile only
    if (t == nt - 1) {
      const int k0 = t << 6;
#pragma unroll
      for (int mi = 0; mi < 4; ++mi)
#pragma unroll
        for (int r = 0; r < 4; ++r) {
          int kvg = k0 + mi * 16 + g * 4 + r;
          s[mi][r] = (kvg <= qg) ? s[mi][r] : -1e30f;
        }
    }

    // per-lane partial max; any-lane-overflow vote (sound)
    float pmax = -1e30f;
#pragma unroll
    for (int mi = 0; mi < 4; ++mi)
#pragma unroll
      for (int r = 0; r < 4; ++r) pmax = fmaxf(pmax, s[mi][r]);

    if (!__all(pmax <= m_run + 8.0f)) {  // defer-max (T13), rare path
      float tmax = fmaxf(pmax, __shfl_xor(pmax, 16));
      tmax = fmaxf(tmax, __shfl_xor(tmax, 32));
      float m_new = fmaxf(m_run, tmax);
      float corr = __builtin_amdgcn_exp2f(m_run - m_new);
      l_run *= corr;
#pragma unroll
      for (int mi = 0; mi < 4; ++mi)
#pragma unroll
        for (int r = 0; r < 4; ++r) ot[mi][r] *= corr;
      m_run = m_new;
    }

    // P = exp2(s - m), pack via v_cvt_pk_bf16_f32, swizzled b64 LDS writes
    float tsum = 0.f;
#pragma unroll
    for (int mi = 0; mi < 4; ++mi) {
      float p0 = __builtin_amdgcn_exp2f(s[mi][0] - m_run);
      float p1 = __builtin_amdgcn_exp2f(s[mi][1] - m_run);
      float p2 = __builtin_amdgcn_exp2f(s[mi][2] - m_run);
      float p3 = __builtin_amdgcn_exp2f(s[mi][3] - m_run);
      tsum += (p0 + p1) + (p2 + p3);
      uint2 pk;
      pk.x = cvt_pk_bf16(p0, p1);
      pk.y = cvt_pk_bf16(p2, p3);
      *reinterpret_cast<uint2*>((char*)Ps + qrow * 128 + ((mi * 32 + g * 8) ^ sP)) = pk;
    }
    l_run += tsum;

    // O^T += V^T · P^T
    __builtin_amdgcn_s_setprio(1);
#pragma unroll
    for (int kk = 0; kk < 2; ++kk) {
      bf16x8 pfr = *reinterpret_cast<const bf16x8*>(
          (const char*)Ps + qrow * 128 + ((kk * 64 + g * 16) ^ sP));
#pragma unroll
      for (int mi = 0; mi < 4; ++mi) {
        int row = mi * 16 + l15;
        bf16x8 vf = *reinterpret_cast<const bf16x8*>(
            (const char*)VtC + row * 128 + ((kk * 64 + g * 16) ^ ((row & 7) << 4)));
        ot[mi] = __builtin_amdgcn_mfma_f32_16x16x32_bf16(vf, pfr, ot[mi], 0, 0, 0);
      }
    }
    __builtin_amdgcn_s_setprio(0);

    if (pf) write_vt(Vt + ((t + 1) & 1) * VT_SZ, kvL, d8, va, vb);
    __syncthreads();
  }

  // reduce per-lane l partials (once per q-tile)
  float l_tot = l_run + __shfl_xor(l_run, 16);
  l_tot += __shfl_xor(l_tot, 32);
  float inv_l = 1.0f / l_tot;

  // epilogue: O^T -> LDS (reuse Ks, swizzled) -> coalesced stores
#pragma unroll
  for (int mi = 0; mi < 4; ++mi) {
    uint2 pk;
    pk.x = cvt_pk_bf16(ot[mi][0] * inv_l, ot[mi][1] * inv_l);
    pk.y = cvt_pk_bf16(ot[mi][2] * inv_l, ot[mi][3] * inv_l);
    int b0 = (mi * 32 + g * 8) ^ sP;
    *reinterpret_cast<uint2*>((char*)Ks + qrow * 128 + b0) = pk;
  }
  __syncthreads();
#pragma unroll
  for (int i = 0; i < 2; ++i) {
    int t = tid + i * 256;
    int row = t >> 3;
    int cb = (t & 7) << 4;
    int sw = cb ^ ((row & 7) << 4);
    bf16x8 vv = *reinterpret_cast<const bf16x8*>((const char*)Ks + row * 128 + sw);
    *reinterpret_cast<bf16x8*>(O + ((size_t)(b * 2048 + q0 + row)) * 1024 + h * 64 + (cb >> 1)) = vv;
  }
}

// ---------------- launch ----------------
extern "C" void kernel_launch(void* const* d_in, const int* in_sizes, int n_in,
                              void* d_out, int out_size, void* d_ws, size_t ws_size,
                              hipStream_t stream) {
  const float* x = (const float*)d_in[0];
  const float* w_qkv = (const float*)d_in[1];
  const float* b_qkv = (const float*)d_in[2];
  const float* w_out = (const float*)d_in[3];
  const float* b_out = (const float*)d_in[4];
  float* out = (float*)d_out;
  char* ws = (char*)d_ws;

  unsigned short* xb    = (unsigned short*)d_out;            // dead before GEMM2 writes
  unsigned short* wqkvT = (unsigned short*)(ws);             //  6 MB
  unsigned short* woT   = (unsigned short*)(ws + 6291456);   //  2 MB
  unsigned short* q_buf = (unsigned short*)(ws + 8388608);   //  8 MB
  unsigned short* k_buf = (unsigned short*)(ws + 16777216);  //  8 MB
  unsigned short* v_buf = (unsigned short*)(ws + 25165824);  //  8 MB
  unsigned short* aout  = (unsigned short*)(ws + 33554432);  //  8 MB -> 40 MB total

  prep_kernel<<<dim3(8192), dim3(256), 0, stream>>>(x, w_qkv, w_out, xb, wqkvT, woT);

  gemm_bf16<0, 128><<<dim3(24, 32), dim3(256), 0, stream>>>(
      xb, wqkvT, b_qkv, q_buf, k_buf, v_buf, nullptr);

  attn_fwd<<<dim3(1024), dim3(256), 0, stream>>>(q_buf, k_buf, v_buf, aout);

  gemm_bf16<1, 64><<<dim3(16, 32), dim3(256), 0, stream>>>(
      aout, woT, b_out, nullptr, nullptr, nullptr, out);
}